// Round 12
// baseline (123.679 us; speedup 1.0000x reference)
//
#include <hip/hip_runtime.h>
#include <math.h>

// TDVP_V2: BATCH=16384 chains, N=64 sites, D=4, DIN=DOUT=2.
// v12: TWO chains per thread (dual-stream ILP + shared A/B loads).
//   cp = tid&15 : chain-pair (chains cp and cp+16 of the block's 32)
//   s  = tid>>4 : segment 0..7 (8 sites each)
//   block = 128 threads (16 pairs x 8 segs), grid = 512 -> 2 blocks/CU.
// Rationale (R11 post-mortem): wave count is NOT binding — per-thread VALU
// + un-hidden load latency is. Two independent chains per thread give the
// scheduler a second instruction stream for every dependent chain, and A/B
// loads (chain-independent) are issued once for two chains' FMA work.
// LDS: ONE 16.6 KB buffer, reused x -> segment-product table -> y:
//   x/y : [chain]*130 + 2*site   (coalesced in/out, v9-proven)
//   sP  : [t]*520 + [e]*32 + ch  (banks (8t+ch)%32 -> <=2/bank; scan reads
//         are same-address broadcasts across the wave = free)
// Phases: stage x | read x | P products (2 chains, shared A) | scans (2
// chains interleaved) | backward ar pre-walk | forward fused epilogue
// (shared B) | coalesced y out.  Math identical to v10 (absmax-proven).

#define EPS 1e-6f

__global__ __launch_bounds__(128)
void tdvp_kernel(const float* __restrict__ x,
                 const float* __restrict__ A,
                 const float* __restrict__ Bw,
                 const float* __restrict__ scale,
                 float* __restrict__ y)
{
    __shared__ float sBuf[32 * 130];    // 16.6 KB, reused 3 ways

    const int tid = threadIdx.x;        // 0..127
    const int cp  = tid & 15;
    const int s   = tid >> 4;           // 0..7
    const int n0  = s * 8;
    const int c0  = cp, c1 = cp + 16;

    // ---- stage x: fully coalesced (32 chains x 32 float4) ----------------
    {
        const float4* xg = (const float4*)x + (size_t)blockIdx.x * 1024;
        #pragma unroll
        for (int it = 0; it < 8; ++it) {
            const int g = it * 128 + tid;
            const float4 v = xg[g];
            const int c = g >> 5, f = (g & 31) * 4;
            *(float2*)&sBuf[c * 130 + f]     = make_float2(v.x, v.y);
            *(float2*)&sBuf[c * 130 + f + 2] = make_float2(v.z, v.w);
        }
    }
    __syncthreads();

    // ---- both chains' 8 sites, normalized --------------------------------
    float xa0[8], xc0[8], xa1[8], xc1[8];
    #pragma unroll
    for (int k = 0; k < 8; ++k) {
        float2 v = *(const float2*)&sBuf[c0 * 130 + 2 * (n0 + k)];
        float inr = 1.f / sqrtf(v.x * v.x + v.y * v.y);
        xa0[k] = v.x * inr; xc0[k] = v.y * inr;
        v = *(const float2*)&sBuf[c1 * 130 + 2 * (n0 + k)];
        inr = 1.f / sqrtf(v.x * v.x + v.y * v.y);
        xa1[k] = v.x * inr; xc1[k] = v.y * inr;
    }
    __syncthreads();

    // ---- phase 1: segment products for both chains (shared A loads) ------
    {
        float P0[16], P1[16];
        {
            const float4* Aq = (const float4*)A + (size_t)n0 * 8;
            #pragma unroll
            for (int t = 0; t < 8; ++t) {
                const float4 q = Aq[t];
                P0[2*t]   = fmaf(xc0[0], q.y, xa0[0] * q.x);
                P0[2*t+1] = fmaf(xc0[0], q.w, xa0[0] * q.z);
                P1[2*t]   = fmaf(xc1[0], q.y, xa1[0] * q.x);
                P1[2*t+1] = fmaf(xc1[0], q.w, xa1[0] * q.z);
            }
        }
        #pragma unroll
        for (int k = 1; k < 8; ++k) {
            const float4* Ak = (const float4*)A + (size_t)(n0 + k) * 8;
            float M0[16], M1[16];
            #pragma unroll
            for (int t = 0; t < 8; ++t) {
                const float4 q = Ak[t];
                M0[2*t]   = fmaf(xc0[k], q.y, xa0[k] * q.x);
                M0[2*t+1] = fmaf(xc0[k], q.w, xa0[k] * q.z);
                M1[2*t]   = fmaf(xc1[k], q.y, xa1[k] * q.x);
                M1[2*t+1] = fmaf(xc1[k], q.w, xa1[k] * q.z);
            }
            float Pn[16];
            #pragma unroll
            for (int i = 0; i < 4; ++i)
                #pragma unroll
                for (int j = 0; j < 4; ++j) {
                    float acc = P0[i*4] * M0[j];
                    acc = fmaf(P0[i*4+1], M0[4+j],  acc);
                    acc = fmaf(P0[i*4+2], M0[8+j],  acc);
                    acc = fmaf(P0[i*4+3], M0[12+j], acc);
                    Pn[i*4+j] = acc;
                }
            #pragma unroll
            for (int e = 0; e < 16; ++e) P0[e] = Pn[e];
            #pragma unroll
            for (int i = 0; i < 4; ++i)
                #pragma unroll
                for (int j = 0; j < 4; ++j) {
                    float acc = P1[i*4] * M1[j];
                    acc = fmaf(P1[i*4+1], M1[4+j],  acc);
                    acc = fmaf(P1[i*4+2], M1[8+j],  acc);
                    acc = fmaf(P1[i*4+3], M1[12+j], acc);
                    Pn[i*4+j] = acc;
                }
            #pragma unroll
            for (int e = 0; e < 16; ++e) P1[e] = Pn[e];
        }
        float s0 = 0.f, s1 = 0.f;
        #pragma unroll
        for (int e = 0; e < 16; ++e) { s0 = fmaf(P0[e], P0[e], s0);
                                       s1 = fmaf(P1[e], P1[e], s1); }
        const float r0 = 1.f / (sqrtf(s0) + 1e-30f);
        const float r1 = 1.f / (sqrtf(s1) + 1e-30f);
        #pragma unroll
        for (int e = 0; e < 16; ++e) {
            sBuf[s * 520 + e * 32 + c0] = P0[e] * r0;
            sBuf[s * 520 + e * 32 + c1] = P1[e] * r1;
        }
    }
    __syncthreads();

    // ---- phase 2: prefix / suffix vector scans, both chains interleaved --
    float v00 = 1.f, v01 = 0.f, v02 = 0.f, v03 = 0.f;   // chain0 prefix
    float v10 = 1.f, v11 = 0.f, v12 = 0.f, v13 = 0.f;   // chain1 prefix
    #pragma unroll 1
    for (int t = 0; t < s; ++t) {
        const float* pp = &sBuf[t * 520 + cp];
        const float p0  = pp[0],    p1  = pp[32],   p2  = pp[64],   p3  = pp[96];
        const float p4  = pp[128],  p5  = pp[160],  p6  = pp[192],  p7  = pp[224];
        const float p8  = pp[256],  p9  = pp[288],  p10 = pp[320],  p11 = pp[352];
        const float p12 = pp[384],  p13 = pp[416],  p14 = pp[448],  p15 = pp[480];
        const float q0  = pp[16],   q1  = pp[48],   q2  = pp[80],   q3  = pp[112];
        const float q4  = pp[144],  q5  = pp[176],  q6  = pp[208],  q7  = pp[240];
        const float q8  = pp[272],  q9  = pp[304],  q10 = pp[336],  q11 = pp[368];
        const float q12 = pp[400],  q13 = pp[432],  q14 = pp[464],  q15 = pp[496];
        float w0 = v00*p0 + v01*p4 + v02*p8  + v03*p12;
        float w1 = v00*p1 + v01*p5 + v02*p9  + v03*p13;
        float w2 = v00*p2 + v01*p6 + v02*p10 + v03*p14;
        float w3 = v00*p3 + v01*p7 + v02*p11 + v03*p15;
        float rn = 1.f / (sqrtf(w0*w0 + w1*w1 + w2*w2 + w3*w3) + 1e-30f);
        v00 = w0*rn; v01 = w1*rn; v02 = w2*rn; v03 = w3*rn;
        w0 = v10*q0 + v11*q4 + v12*q8  + v13*q12;
        w1 = v10*q1 + v11*q5 + v12*q9  + v13*q13;
        w2 = v10*q2 + v11*q6 + v12*q10 + v13*q14;
        w3 = v10*q3 + v11*q7 + v12*q11 + v13*q15;
        rn = 1.f / (sqrtf(w0*w0 + w1*w1 + w2*w2 + w3*w3) + 1e-30f);
        v10 = w0*rn; v11 = w1*rn; v12 = w2*rn; v13 = w3*rn;
    }
    float u00 = 1.f, u01 = 0.f, u02 = 0.f, u03 = 0.f;   // chain0 suffix
    float u10 = 1.f, u11 = 0.f, u12 = 0.f, u13 = 0.f;   // chain1 suffix
    #pragma unroll 1
    for (int t = 7; t > s; --t) {
        const float* pp = &sBuf[t * 520 + cp];
        const float p0  = pp[0],    p1  = pp[32],   p2  = pp[64],   p3  = pp[96];
        const float p4  = pp[128],  p5  = pp[160],  p6  = pp[192],  p7  = pp[224];
        const float p8  = pp[256],  p9  = pp[288],  p10 = pp[320],  p11 = pp[352];
        const float p12 = pp[384],  p13 = pp[416],  p14 = pp[448],  p15 = pp[480];
        const float q0  = pp[16],   q1  = pp[48],   q2  = pp[80],   q3  = pp[112];
        const float q4  = pp[144],  q5  = pp[176],  q6  = pp[208],  q7  = pp[240];
        const float q8  = pp[272],  q9  = pp[304],  q10 = pp[336],  q11 = pp[368];
        const float q12 = pp[400],  q13 = pp[432],  q14 = pp[464],  q15 = pp[496];
        float w0 = p0*u00  + p1*u01  + p2*u02  + p3*u03;
        float w1 = p4*u00  + p5*u01  + p6*u02  + p7*u03;
        float w2 = p8*u00  + p9*u01  + p10*u02 + p11*u03;
        float w3 = p12*u00 + p13*u01 + p14*u02 + p15*u03;
        float rn = 1.f / (sqrtf(w0*w0 + w1*w1 + w2*w2 + w3*w3) + 1e-30f);
        u00 = w0*rn; u01 = w1*rn; u02 = w2*rn; u03 = w3*rn;
        w0 = q0*u10  + q1*u11  + q2*u12  + q3*u13;
        w1 = q4*u10  + q5*u11  + q6*u12  + q7*u13;
        w2 = q8*u10  + q9*u11  + q10*u12 + q11*u13;
        w3 = q12*u10 + q13*u11 + q14*u12 + q15*u13;
        rn = 1.f / (sqrtf(w0*w0 + w1*w1 + w2*w2 + w3*w3) + 1e-30f);
        u10 = w0*rn; u11 = w1*rn; u12 = w2*rn; u13 = w3*rn;
    }

    // ---- backward pre-walk: per-site ar for both chains (shared A) -------
    float a0A[8], a0B[8], a0C[8], a0D[8];   // chain0 ar per site
    float a1A[8], a1B[8], a1C[8], a1D[8];   // chain1 ar per site
    #pragma unroll
    for (int kk = 7; kk >= 0; --kk) {
        const int n = n0 + kk;
        float rn = 1.f / (sqrtf(u00*u00 + u01*u01 + u02*u02 + u03*u03) + EPS);
        a0A[kk] = u00*rn; a0B[kk] = u01*rn; a0C[kk] = u02*rn; a0D[kk] = u03*rn;
        rn = 1.f / (sqrtf(u10*u10 + u11*u11 + u12*u12 + u13*u13) + EPS);
        a1A[kk] = u10*rn; a1B[kk] = u11*rn; a1C[kk] = u12*rn; a1D[kk] = u13*rn;
        if (n == 63) { a0A[kk] = 1.f; a0B[kk] = a0C[kk] = a0D[kk] = 0.f;
                       a1A[kk] = 1.f; a1B[kk] = a1C[kk] = a1D[kk] = 0.f; }
        if (kk > 0) {
            const float4* Ak = (const float4*)A + (size_t)n * 8;
            float M0[16], M1[16];
            #pragma unroll
            for (int t = 0; t < 8; ++t) {
                const float4 q = Ak[t];
                M0[2*t]   = fmaf(xc0[kk], q.y, xa0[kk] * q.x);
                M0[2*t+1] = fmaf(xc0[kk], q.w, xa0[kk] * q.z);
                M1[2*t]   = fmaf(xc1[kk], q.y, xa1[kk] * q.x);
                M1[2*t+1] = fmaf(xc1[kk], q.w, xa1[kk] * q.z);
            }
            float t0 = M0[0]*u00  + M0[1]*u01  + M0[2]*u02  + M0[3]*u03;
            float t1 = M0[4]*u00  + M0[5]*u01  + M0[6]*u02  + M0[7]*u03;
            float t2 = M0[8]*u00  + M0[9]*u01  + M0[10]*u02 + M0[11]*u03;
            float t3 = M0[12]*u00 + M0[13]*u01 + M0[14]*u02 + M0[15]*u03;
            u00 = t0; u01 = t1; u02 = t2; u03 = t3;
            t0 = M1[0]*u10  + M1[1]*u11  + M1[2]*u12  + M1[3]*u13;
            t1 = M1[4]*u10  + M1[5]*u11  + M1[6]*u12  + M1[7]*u13;
            t2 = M1[8]*u10  + M1[9]*u11  + M1[10]*u12 + M1[11]*u13;
            t3 = M1[12]*u10 + M1[13]*u11 + M1[14]*u12 + M1[15]*u13;
            u10 = t0; u11 = t1; u12 = t2; u13 = t3;
        }
    }
    __syncthreads();    // sP dead; sBuf becomes the y buffer

    // ---- forward fused epilogue (shared B loads) -------------------------
    const float sc = scale[0];
    #pragma unroll
    for (int kk = 0; kk < 8; ++kk) {
        const int n = n0 + kk;

        float rn = 1.f / (sqrtf(v00*v00 + v01*v01 + v02*v02 + v03*v03) + EPS);
        float vv0A = v00*rn, vv0B = v01*rn, vv0C = v02*rn, vv0D = v03*rn;
        rn = 1.f / (sqrtf(v10*v10 + v11*v11 + v12*v12 + v13*v13) + EPS);
        float vv1A = v10*rn, vv1B = v11*rn, vv1C = v12*rn, vv1D = v13*rn;
        if (n == 0) { vv0A = 1.f; vv0B = vv0C = vv0D = 0.f;
                      vv1A = 1.f; vv1B = vv1C = vv1D = 0.f; }

        const float vv0[4] = {vv0A, vv0B, vv0C, vv0D};
        const float vv1[4] = {vv1A, vv1B, vv1C, vv1D};
        const float aa0[4] = {a0A[kk], a0B[kk], a0C[kk], a0D[kk]};
        const float aa1[4] = {a1A[kk], a1B[kk], a1C[kk], a1D[kk]};

        const float4* Bq = (const float4*)Bw + (size_t)n * 16;
        float G00 = 0.f, G01 = 0.f, G10 = 0.f, G11 = 0.f;   // chain0 H
        float K00 = 0.f, K01 = 0.f, K10 = 0.f, K11 = 0.f;   // chain1 H
        #pragma unroll
        for (int half = 0; half < 2; ++half) {
            float4 bq[8];
            #pragma unroll
            for (int t = 0; t < 8; ++t) bq[t] = Bq[half * 8 + t];
            #pragma unroll
            for (int i2 = 0; i2 < 2; ++i2) {
                const int i = half * 2 + i2;
                #pragma unroll
                for (int l = 0; l < 4; ++l) {
                    const float4 q = bq[i2 * 4 + l];
                    const float ca = vv0[i] * aa0[l];
                    G00 = fmaf(ca, q.x, G00); G01 = fmaf(ca, q.y, G01);
                    G10 = fmaf(ca, q.z, G10); G11 = fmaf(ca, q.w, G11);
                    const float cb = vv1[i] * aa1[l];
                    K00 = fmaf(cb, q.x, K00); K01 = fmaf(cb, q.y, K01);
                    K10 = fmaf(cb, q.z, K10); K11 = fmaf(cb, q.w, K11);
                }
            }
        }
        float rh = sc / (sqrtf(G00*G00 + G01*G01 + G10*G10 + G11*G11) + EPS);
        G00 *= rh; G01 *= rh; G10 *= rh; G11 *= rh;
        if (__builtin_isnan(G00)) G00 = 0.f;
        if (__builtin_isnan(G01)) G01 = 0.f;
        if (__builtin_isnan(G10)) G10 = 0.f;
        if (__builtin_isnan(G11)) G11 = 0.f;
        G00 = fmaxf(G00, 0.f); G01 = fmaxf(G01, 0.f);
        G10 = fmaxf(G10, 0.f); G11 = fmaxf(G11, 0.f);
        rh = sc / (sqrtf(K00*K00 + K01*K01 + K10*K10 + K11*K11) + EPS);
        K00 *= rh; K01 *= rh; K10 *= rh; K11 *= rh;
        if (__builtin_isnan(K00)) K00 = 0.f;
        if (__builtin_isnan(K01)) K01 = 0.f;
        if (__builtin_isnan(K10)) K10 = 0.f;
        if (__builtin_isnan(K11)) K11 = 0.f;
        K00 = fmaxf(K00, 0.f); K01 = fmaxf(K01, 0.f);
        K10 = fmaxf(K10, 0.f); K11 = fmaxf(K11, 0.f);

        *(float2*)&sBuf[c0 * 130 + 2 * n] =
            make_float2(fmaf(G01, xc0[kk], G00 * xa0[kk]),
                        fmaf(G11, xc0[kk], G10 * xa0[kk]));
        *(float2*)&sBuf[c1 * 130 + 2 * n] =
            make_float2(fmaf(K01, xc1[kk], K00 * xa1[kk]),
                        fmaf(K11, xc1[kk], K10 * xa1[kk]));

        if (kk < 7) {   // vl advance: v <- v^T M[n]  (shared A load)
            const float4* Ak = (const float4*)A + (size_t)n * 8;
            float M0[16], M1[16];
            #pragma unroll
            for (int t = 0; t < 8; ++t) {
                const float4 q = Ak[t];
                M0[2*t]   = fmaf(xc0[kk], q.y, xa0[kk] * q.x);
                M0[2*t+1] = fmaf(xc0[kk], q.w, xa0[kk] * q.z);
                M1[2*t]   = fmaf(xc1[kk], q.y, xa1[kk] * q.x);
                M1[2*t+1] = fmaf(xc1[kk], q.w, xa1[kk] * q.z);
            }
            float t0 = v00*M0[0] + v01*M0[4] + v02*M0[8]  + v03*M0[12];
            float t1 = v00*M0[1] + v01*M0[5] + v02*M0[9]  + v03*M0[13];
            float t2 = v00*M0[2] + v01*M0[6] + v02*M0[10] + v03*M0[14];
            float t3 = v00*M0[3] + v01*M0[7] + v02*M0[11] + v03*M0[15];
            v00 = t0; v01 = t1; v02 = t2; v03 = t3;
            t0 = v10*M1[0] + v11*M1[4] + v12*M1[8]  + v13*M1[12];
            t1 = v10*M1[1] + v11*M1[5] + v12*M1[9]  + v13*M1[13];
            t2 = v10*M1[2] + v11*M1[6] + v12*M1[10] + v13*M1[14];
            t3 = v10*M1[3] + v11*M1[7] + v12*M1[11] + v13*M1[15];
            v10 = t0; v11 = t1; v12 = t2; v13 = t3;
        }
    }
    __syncthreads();

    // ---- y out: fully coalesced float4 stores ----------------------------
    {
        float4* yg = (float4*)y + (size_t)blockIdx.x * 1024;
        #pragma unroll
        for (int it = 0; it < 8; ++it) {
            const int g = it * 128 + tid;
            const int c = g >> 5, f = (g & 31) * 4;
            const float2 a = *(const float2*)&sBuf[c * 130 + f];
            const float2 b = *(const float2*)&sBuf[c * 130 + f + 2];
            yg[g] = make_float4(a.x, a.y, b.x, b.y);
        }
    }
}

extern "C" void kernel_launch(void* const* d_in, const int* in_sizes, int n_in,
                              void* d_out, int out_size, void* d_ws, size_t ws_size,
                              hipStream_t stream) {
    const float* x     = (const float*)d_in[0];
    const float* A     = (const float*)d_in[1];
    const float* B     = (const float*)d_in[2];
    const float* scale = (const float*)d_in[3];
    float* yp = (float*)d_out;
    const int batch  = in_sizes[0] / 128;    // 16384
    const int blocks = batch / 32;           // 512 blocks x 128 threads
    tdvp_kernel<<<blocks, 128, 0, stream>>>(x, A, B, scale, yp);
}

// Round 13
// 78.938 us; speedup vs baseline: 1.5668x; 1.5668x over previous
//
#include <hip/hip_runtime.h>
#include <math.h>

// TDVP_V2: BATCH=16384 chains, N=64 sites, D=4, DIN=DOUT=2.
// v13 = v10 (best, JSON 82.3) + A/B staged in LDS.
// v12 lesson: 2 chains/thread spilled (VGPR=256, 136 MB scratch) AND halved
// wave count. Reverted. v10 audit: 43k cyc/SIMD, 10.8k VALU (25%) — the
// stall is ~24 L2-hit wait events/wave (A-build batches + B epilogue
// chunks, ~200 cyc each) barely covered at 2 waves/SIMD. Fix: A (8 KB) +
// B (16 KB) live in LDS -> broadcast ds_read_b128 (~12 cyc, half-wave
// same-address = free; 2 addr/bank across halves = free per m136).
//   bb = tid&31 : chain-in-block (32 chains), s = tid>>5 : segment 0..7.
//   grid = 512 blocks x 256 threads -> 2 blocks/CU, 2 waves/SIMD.
// LDS: sP 16 KB + sXY 16.6 KB + sA 8 KB + sB 16 KB = 57.3 KB (< 64 KB
// proven envelope; 2 blocks/CU preserved).
// Phases (v10 verbatim except A/B source):
//   stage x+A+B | build M[0..7] once -> regs | P product (norm) -> sP |
//   prefix/suffix vector scans | forward walk (vl) | backward walk +
//   epilogue (B from LDS) -> sXY | coalesced y out.

#define EPS 1e-6f

__global__ __launch_bounds__(256)
void tdvp_kernel(const float* __restrict__ x,
                 const float* __restrict__ A,
                 const float* __restrict__ Bw,
                 const float* __restrict__ scale,
                 float* __restrict__ y)
{
    __shared__ float  sP[8 * 16 * 32];   // [t][e][bb]      16 KB
    __shared__ float  sXY[32 * 130];     // [chain][2*site] 16.6 KB
    __shared__ float4 sA[64 * 8];        // A[site][8]       8 KB
    __shared__ float4 sB[64 * 16];       // B[site][16]     16 KB

    const int tid = threadIdx.x;
    const int bb  = tid & 31;
    const int s   = tid >> 5;            // 0..7

    // ---- stage x (coalesced) + A + B into LDS ----------------------------
    {
        const float4* xg = (const float4*)x + (size_t)blockIdx.x * 1024;
        #pragma unroll
        for (int it = 0; it < 4; ++it) {
            const int g = it * 256 + tid;
            const float4 v = xg[g];
            const int c = g >> 5, f = (g & 31) * 4;
            *(float2*)&sXY[c * 130 + f]     = make_float2(v.x, v.y);
            *(float2*)&sXY[c * 130 + f + 2] = make_float2(v.z, v.w);
        }
        const float4* Ag = (const float4*)A;     // 512 float4
        #pragma unroll
        for (int it = 0; it < 2; ++it)
            sA[it * 256 + tid] = Ag[it * 256 + tid];
        const float4* Bg = (const float4*)Bw;    // 1024 float4
        #pragma unroll
        for (int it = 0; it < 4; ++it)
            sB[it * 256 + tid] = Bg[it * 256 + tid];
    }
    __syncthreads();

    // ---- my 8 sites from LDS, normalized --------------------------------
    const int n0 = s * 8;
    float xa[8], xc[8];
    #pragma unroll
    for (int k = 0; k < 8; ++k) {
        const float2 v = *(const float2*)&sXY[bb * 130 + s * 16 + 2 * k];
        const float inr = 1.f / sqrtf(v.x * v.x + v.y * v.y);
        xa[k] = v.x * inr; xc[k] = v.y * inr;
    }

    // ---- build all 8 M matrices ONCE into registers (A from LDS) ---------
    float M[8][16];
    #pragma unroll
    for (int k = 0; k < 8; ++k) {
        const float4* Aq = &sA[(n0 + k) * 8];
        #pragma unroll
        for (int t = 0; t < 8; ++t) {
            const float4 q = Aq[t];
            M[k][2*t]     = fmaf(xc[k], q.y, xa[k] * q.x);
            M[k][2*t + 1] = fmaf(xc[k], q.w, xa[k] * q.z);
        }
    }

    // ---- phase 1: segment product P = M[0]..M[7] (normalized) -> sP ------
    {
        float P[16];
        #pragma unroll
        for (int e = 0; e < 16; ++e) P[e] = M[0][e];
        #pragma unroll
        for (int k = 1; k < 8; ++k) {
            float Pn[16];
            #pragma unroll
            for (int i = 0; i < 4; ++i) {
                #pragma unroll
                for (int j = 0; j < 4; ++j) {
                    float acc = P[i*4] * M[k][j];
                    acc = fmaf(P[i*4+1], M[k][4+j],  acc);
                    acc = fmaf(P[i*4+2], M[k][8+j],  acc);
                    acc = fmaf(P[i*4+3], M[k][12+j], acc);
                    Pn[i*4+j] = acc;
                }
            }
            #pragma unroll
            for (int e = 0; e < 16; ++e) P[e] = Pn[e];
        }
        float ss = 0.f;
        #pragma unroll
        for (int e = 0; e < 16; ++e) ss = fmaf(P[e], P[e], ss);
        const float rn = 1.f / (sqrtf(ss) + 1e-30f);
        #pragma unroll
        for (int e = 0; e < 16; ++e)
            sP[s * 512 + e * 32 + bb] = P[e] * rn;
    }
    __syncthreads();

    // ---- phase 2: per-thread prefix / suffix vector scans ---------------
    float v0 = 1.f, v1 = 0.f, v2 = 0.f, v3 = 0.f;
    #pragma unroll 1
    for (int t = 0; t < s; ++t) {
        const float* pp = &sP[t * 512 + bb];
        const float p0  = pp[0],      p1  = pp[32],     p2  = pp[64],     p3  = pp[96];
        const float p4  = pp[128],    p5  = pp[160],    p6  = pp[192],    p7  = pp[224];
        const float p8  = pp[256],    p9  = pp[288],    p10 = pp[320],    p11 = pp[352];
        const float p12 = pp[384],    p13 = pp[416],    p14 = pp[448],    p15 = pp[480];
        const float w0 = v0*p0 + v1*p4 + v2*p8  + v3*p12;
        const float w1 = v0*p1 + v1*p5 + v2*p9  + v3*p13;
        const float w2 = v0*p2 + v1*p6 + v2*p10 + v3*p14;
        const float w3 = v0*p3 + v1*p7 + v2*p11 + v3*p15;
        const float rn = 1.f / (sqrtf(w0*w0 + w1*w1 + w2*w2 + w3*w3) + 1e-30f);
        v0 = w0*rn; v1 = w1*rn; v2 = w2*rn; v3 = w3*rn;
    }
    float u0 = 1.f, u1 = 0.f, u2 = 0.f, u3 = 0.f;
    #pragma unroll 1
    for (int t = 7; t > s; --t) {
        const float* pp = &sP[t * 512 + bb];
        const float p0  = pp[0],      p1  = pp[32],     p2  = pp[64],     p3  = pp[96];
        const float p4  = pp[128],    p5  = pp[160],    p6  = pp[192],    p7  = pp[224];
        const float p8  = pp[256],    p9  = pp[288],    p10 = pp[320],    p11 = pp[352];
        const float p12 = pp[384],    p13 = pp[416],    p14 = pp[448],    p15 = pp[480];
        const float w0 = p0*u0  + p1*u1  + p2*u2  + p3*u3;
        const float w1 = p4*u0  + p5*u1  + p6*u2  + p7*u3;
        const float w2 = p8*u0  + p9*u1  + p10*u2 + p11*u3;
        const float w3 = p12*u0 + p13*u1 + p14*u2 + p15*u3;
        const float rn = 1.f / (sqrtf(w0*w0 + w1*w1 + w2*w2 + w3*w3) + 1e-30f);
        u0 = w0*rn; u1 = w1*rn; u2 = w2*rn; u3 = w3*rn;
    }

    // ---- phase 3a: forward walk, store vl per site (cached M) ------------
    float vlA[8], vlB[8], vlC[8], vlD[8];
    {
        float a0 = v0, a1 = v1, a2 = v2, a3 = v3;
        #pragma unroll
        for (int k = 0; k < 8; ++k) {
            vlA[k] = a0; vlB[k] = a1; vlC[k] = a2; vlD[k] = a3;
            if (k == 7) break;
            const float t0 = a0*M[k][0] + a1*M[k][4] + a2*M[k][8]  + a3*M[k][12];
            const float t1 = a0*M[k][1] + a1*M[k][5] + a2*M[k][9]  + a3*M[k][13];
            const float t2 = a0*M[k][2] + a1*M[k][6] + a2*M[k][10] + a3*M[k][14];
            const float t3 = a0*M[k][3] + a1*M[k][7] + a2*M[k][11] + a3*M[k][15];
            a0 = t0; a1 = t1; a2 = t2; a3 = t3;
        }
    }

    // ---- phase 3b: backward walk + fused epilogue (B from LDS) -> sXY ----
    const float sc = scale[0];
    #pragma unroll
    for (int kk = 7; kk >= 0; --kk) {
        const int n = n0 + kk;

        const float arn = 1.f / (sqrtf(u0*u0 + u1*u1 + u2*u2 + u3*u3) + EPS);
        float aa0 = u0*arn, aa1 = u1*arn, aa2 = u2*arn, aa3 = u3*arn;
        if (n == 63) { aa0 = 1.f; aa1 = aa2 = aa3 = 0.f; }

        const float wn = 1.f / (sqrtf(vlA[kk]*vlA[kk] + vlB[kk]*vlB[kk] +
                                      vlC[kk]*vlC[kk] + vlD[kk]*vlD[kk]) + EPS);
        float vv0 = vlA[kk]*wn, vv1 = vlB[kk]*wn, vv2 = vlC[kk]*wn, vv3 = vlD[kk]*wn;
        if (n == 0) { vv0 = 1.f; vv1 = vv2 = vv3 = 0.f; }

        const float vv[4] = {vv0, vv1, vv2, vv3};
        const float aa[4] = {aa0, aa1, aa2, aa3};
        const float4* Bq = &sB[n * 16];
        float H00 = 0.f, H01 = 0.f, H10 = 0.f, H11 = 0.f;
        #pragma unroll
        for (int half = 0; half < 2; ++half) {       // 8 float4 live at a time
            float4 bq[8];
            #pragma unroll
            for (int t = 0; t < 8; ++t) bq[t] = Bq[half * 8 + t];
            #pragma unroll
            for (int i2 = 0; i2 < 2; ++i2) {
                const int i = half * 2 + i2;
                #pragma unroll
                for (int l = 0; l < 4; ++l) {
                    const float  c = vv[i] * aa[l];
                    const float4 q = bq[i2 * 4 + l];
                    H00 = fmaf(c, q.x, H00);
                    H01 = fmaf(c, q.y, H01);
                    H10 = fmaf(c, q.z, H10);
                    H11 = fmaf(c, q.w, H11);
                }
            }
        }
        const float rh = sc / (sqrtf(H00*H00 + H01*H01 + H10*H10 + H11*H11) + EPS);
        H00 *= rh; H01 *= rh; H10 *= rh; H11 *= rh;
        if (__builtin_isnan(H00)) H00 = 0.f;
        if (__builtin_isnan(H01)) H01 = 0.f;
        if (__builtin_isnan(H10)) H10 = 0.f;
        if (__builtin_isnan(H11)) H11 = 0.f;
        H00 = fmaxf(H00, 0.f); H01 = fmaxf(H01, 0.f);
        H10 = fmaxf(H10, 0.f); H11 = fmaxf(H11, 0.f);

        float2 yo;
        yo.x = fmaf(H01, xc[kk], H00 * xa[kk]);
        yo.y = fmaf(H11, xc[kk], H10 * xa[kk]);
        *(float2*)&sXY[bb * 130 + 2 * n] = yo;

        if (kk > 0) {   // u <- M[kk].u  (raw suffix for site n-1)
            const float t0 = M[kk][0]*u0  + M[kk][1]*u1  + M[kk][2]*u2  + M[kk][3]*u3;
            const float t1 = M[kk][4]*u0  + M[kk][5]*u1  + M[kk][6]*u2  + M[kk][7]*u3;
            const float t2 = M[kk][8]*u0  + M[kk][9]*u1  + M[kk][10]*u2 + M[kk][11]*u3;
            const float t3 = M[kk][12]*u0 + M[kk][13]*u1 + M[kk][14]*u2 + M[kk][15]*u3;
            u0 = t0; u1 = t1; u2 = t2; u3 = t3;
        }
    }
    __syncthreads();

    // ---- y out: fully coalesced float4 stores ----------------------------
    {
        float4* yg = (float4*)y + (size_t)blockIdx.x * 1024;
        #pragma unroll
        for (int it = 0; it < 4; ++it) {
            const int g = it * 256 + tid;
            const int c = g >> 5, f = (g & 31) * 4;
            const float2 a = *(const float2*)&sXY[c * 130 + f];
            const float2 b = *(const float2*)&sXY[c * 130 + f + 2];
            yg[g] = make_float4(a.x, a.y, b.x, b.y);
        }
    }
}

extern "C" void kernel_launch(void* const* d_in, const int* in_sizes, int n_in,
                              void* d_out, int out_size, void* d_ws, size_t ws_size,
                              hipStream_t stream) {
    const float* x     = (const float*)d_in[0];
    const float* A     = (const float*)d_in[1];
    const float* B     = (const float*)d_in[2];
    const float* scale = (const float*)d_in[3];
    float* yp = (float*)d_out;
    const int batch  = in_sizes[0] / 128;    // 16384
    const int blocks = batch / 32;           // 512 blocks x 256 threads
    tdvp_kernel<<<blocks, 256, 0, stream>>>(x, A, B, scale, yp);
}